// Round 1
// baseline (41.167 us; speedup 1.0000x reference)
//
#include <hip/hip_runtime.h>

#define NUM_ITEMS 100000
#define NUM_ENTITIES 1000000
#define EMBED_DIM 64
#define BATCH 16384
#define NUM_NEIGHBORS 50

#define RPB 16          // rows (batch items) per block
#define THREADS 256     // 4 waves

__global__ __launch_bounds__(THREADS) void kgat_fused_kernel(
    const int* __restrict__ item_idx,      // [B]
    const int* __restrict__ nbr_idx,       // [B, K]
    const float* __restrict__ item_tab,    // [NUM_ITEMS, D]
    const float* __restrict__ ent_tab,     // [NUM_ENTITIES, D]
    const float* __restrict__ W,           // [D, D] row-major: W[j][d]
    const float* __restrict__ bias,        // [D]
    float* __restrict__ out)               // [B, D]
{
    __shared__ float xs[RPB][EMBED_DIM];        // 4 KB
    __shared__ float Wl[EMBED_DIM][EMBED_DIM + 1]; // 16.25 KB, pad -> (j+d)%32 banks

    const int t    = threadIdx.x;
    const int lane = t & 63;
    const int wave = t >> 6;                 // 0..3
    const int row0 = blockIdx.x * RPB;

    // ---- stage W into LDS (once per block) ----
    #pragma unroll
    for (int i = t; i < EMBED_DIM * EMBED_DIM; i += THREADS) {
        Wl[i >> 6][i & 63] = W[i];
    }

    // ---- phase 1: gather + mean + item add; wave w owns rows w*4 .. w*4+3 ----
    {
        float acc[4] = {0.f, 0.f, 0.f, 0.f};
        const int rbase = row0 + wave * 4;

        #pragma unroll 2
        for (int k = 0; k < NUM_NEIGHBORS; ++k) {
            #pragma unroll
            for (int rr = 0; rr < 4; ++rr) {
                const int idx = nbr_idx[(rbase + rr) * NUM_NEIGHBORS + k];
                acc[rr] += ent_tab[(size_t)idx * EMBED_DIM + lane];
            }
        }

        #pragma unroll
        for (int rr = 0; rr < 4; ++rr) {
            const int it = item_idx[rbase + rr];
            float x = acc[rr] * (1.0f / NUM_NEIGHBORS)
                    + item_tab[(size_t)it * EMBED_DIM + lane];
            xs[wave * 4 + rr][lane] = x;
        }
    }

    __syncthreads();

    // ---- phase 2: y[r][j] = relu( sum_d xs[r][d] * W[j][d] + b[j] ) ----
    // thread t: j = lane, rows {wave, wave+4, wave+8, wave+12}
    {
        const int j = lane;
        const int r0 = wave;
        float a0 = 0.f, a1 = 0.f, a2 = 0.f, a3 = 0.f;

        #pragma unroll
        for (int d = 0; d < EMBED_DIM; ++d) {
            const float w = Wl[j][d];          // (j+d)%32 banks: 2-way, free
            a0 = fmaf(xs[r0     ][d], w, a0);  // xs reads broadcast (uniform addr per wave)
            a1 = fmaf(xs[r0 +  4][d], w, a1);
            a2 = fmaf(xs[r0 +  8][d], w, a2);
            a3 = fmaf(xs[r0 + 12][d], w, a3);
        }

        const float bb = bias[j];
        out[(size_t)(row0 + r0     ) * EMBED_DIM + j] = fmaxf(a0 + bb, 0.f);
        out[(size_t)(row0 + r0 +  4) * EMBED_DIM + j] = fmaxf(a1 + bb, 0.f);
        out[(size_t)(row0 + r0 +  8) * EMBED_DIM + j] = fmaxf(a2 + bb, 0.f);
        out[(size_t)(row0 + r0 + 12) * EMBED_DIM + j] = fmaxf(a3 + bb, 0.f);
    }
}

extern "C" void kernel_launch(void* const* d_in, const int* in_sizes, int n_in,
                              void* d_out, int out_size, void* d_ws, size_t ws_size,
                              hipStream_t stream) {
    const int*   item_idx = (const int*)  d_in[0];
    const int*   nbr_idx  = (const int*)  d_in[1];
    const float* item_tab = (const float*)d_in[2];
    const float* ent_tab  = (const float*)d_in[3];
    const float* W        = (const float*)d_in[4];
    const float* bias     = (const float*)d_in[5];
    float*       out      = (float*)      d_out;

    dim3 grid(BATCH / RPB);   // 1024 blocks
    dim3 block(THREADS);
    kgat_fused_kernel<<<grid, block, 0, stream>>>(
        item_idx, nbr_idx, item_tab, ent_tab, W, bias, out);
}

// Round 2
// 40.921 us; speedup vs baseline: 1.0060x; 1.0060x over previous
//
#include <hip/hip_runtime.h>

#define EMBED_DIM 64
#define BATCH 16384
#define K_NBR 50

#define RPB 16          // rows (batch items) per block
#define THREADS 256     // 4 waves

__global__ __launch_bounds__(THREADS) void kgat_fused_kernel(
    const int* __restrict__ item_idx,      // [B]
    const int* __restrict__ nbr_idx,       // [B, K]
    const float* __restrict__ item_tab,    // [NUM_ITEMS, D]
    const float* __restrict__ ent_tab,     // [NUM_ENTITIES, D]
    const float* __restrict__ W,           // [D, D] row-major: W[j][d]
    const float* __restrict__ bias,        // [D]
    float* __restrict__ out)               // [B, D]
{
    __shared__ int   ids[RPB * K_NBR];                 // 3.2 KB
    __shared__ int   itid[RPB];                        // 64 B
    __shared__ float xs[RPB][EMBED_DIM + 4];           // 4.25 KB, stride 272 B (16B-aligned)
    __shared__ float Wl[EMBED_DIM][EMBED_DIM + 1];     // 16.25 KB, (j+d)%32 banks

    const int t    = threadIdx.x;
    const int lane = t & 63;
    const int wave = t >> 6;                 // 0..3
    const int row0 = blockIdx.x * RPB;

    // ---- stage W, neighbor ids, item ids into LDS (coalesced, once) ----
    #pragma unroll
    for (int i = t; i < EMBED_DIM * EMBED_DIM; i += THREADS)
        Wl[i >> 6][i & 63] = W[i];
    #pragma unroll
    for (int i = t; i < RPB * K_NBR; i += THREADS)
        ids[i] = nbr_idx[(size_t)row0 * K_NBR + i];
    if (t < RPB) itid[t] = item_idx[row0 + t];
    __syncthreads();

    // ---- phase 1: float4 gather + mean + item add ----
    // wave handles 4 rows at once: q = row-in-group (lane>>4), c = dim-quad (lane&15)
    {
        const int q = lane >> 4;
        const int c = lane & 15;
        const int r = wave * 4 + q;          // local row 0..15
        const int idbase = r * K_NBR;

        const float4* __restrict__ ent4  = (const float4*)ent_tab;
        const float4* __restrict__ item4 = (const float4*)item_tab;

        float4 acc = make_float4(0.f, 0.f, 0.f, 0.f);

        #pragma unroll 10
        for (int k = 0; k < K_NBR; ++k) {
            const int idx = ids[idbase + k];            // LDS broadcast (16 lanes/addr)
            const float4 v = ent4[(size_t)idx * (EMBED_DIM / 4) + c];
            acc.x += v.x; acc.y += v.y; acc.z += v.z; acc.w += v.w;
        }

        const int it = itid[r];
        const float4 iv = item4[(size_t)it * (EMBED_DIM / 4) + c];
        const float s = 1.0f / K_NBR;
        float4 x;
        x.x = fmaf(acc.x, s, iv.x);
        x.y = fmaf(acc.y, s, iv.y);
        x.z = fmaf(acc.z, s, iv.z);
        x.w = fmaf(acc.w, s, iv.w);
        *(float4*)&xs[r][c * 4] = x;
    }

    __syncthreads();

    // ---- phase 2: y[r][j] = relu( sum_d xs[r][d] * W[j][d] + b[j] ) ----
    // thread t: j = lane, rows {wave, wave+4, wave+8, wave+12}
    {
        const int j = lane;
        const int r0 = wave;
        float a0 = 0.f, a1 = 0.f, a2 = 0.f, a3 = 0.f;

        #pragma unroll
        for (int d = 0; d < EMBED_DIM; ++d) {
            const float w = Wl[j][d];          // (j+d)%32: 2-way aliasing, free
            a0 = fmaf(xs[r0     ][d], w, a0);  // xs reads are wave-uniform broadcasts
            a1 = fmaf(xs[r0 +  4][d], w, a1);
            a2 = fmaf(xs[r0 +  8][d], w, a2);
            a3 = fmaf(xs[r0 + 12][d], w, a3);
        }

        const float bb = bias[j];
        out[(size_t)(row0 + r0     ) * EMBED_DIM + j] = fmaxf(a0 + bb, 0.f);
        out[(size_t)(row0 + r0 +  4) * EMBED_DIM + j] = fmaxf(a1 + bb, 0.f);
        out[(size_t)(row0 + r0 +  8) * EMBED_DIM + j] = fmaxf(a2 + bb, 0.f);
        out[(size_t)(row0 + r0 + 12) * EMBED_DIM + j] = fmaxf(a3 + bb, 0.f);
    }
}

extern "C" void kernel_launch(void* const* d_in, const int* in_sizes, int n_in,
                              void* d_out, int out_size, void* d_ws, size_t ws_size,
                              hipStream_t stream) {
    const int*   item_idx = (const int*)  d_in[0];
    const int*   nbr_idx  = (const int*)  d_in[1];
    const float* item_tab = (const float*)d_in[2];
    const float* ent_tab  = (const float*)d_in[3];
    const float* W        = (const float*)d_in[4];
    const float* bias     = (const float*)d_in[5];
    float*       out      = (float*)      d_out;

    dim3 grid(BATCH / RPB);   // 1024 blocks
    dim3 block(THREADS);
    kgat_fused_kernel<<<grid, block, 0, stream>>>(
        item_idx, nbr_idx, item_tab, ent_tab, W, bias, out);
}